// Round 6
// baseline (659.523 us; speedup 1.0000x reference)
//
#include <hip/hip_runtime.h>
#include <hip/hip_bf16.h>

typedef _Float16 f16x8 __attribute__((ext_vector_type(8)));
typedef _Float16 f16x4 __attribute__((ext_vector_type(4)));
typedef float f32x4 __attribute__((ext_vector_type(4)));

#define SD 1024              // D == A == 1024
#define SEQ 2048
#define NB 32
#define M_TOTAL (NB * SEQ)   // 65536
#define BMm 128
#define BNn 128
#define NCT (SD / BNn)       // 8 col-tiles
#define NRT (M_TOTAL / BMm)  // 512 row-tiles
#define NKS (SD / 64)        // 16 K-steps of BK=64
#define LDS_BUF 32768        // A 16KB + B 16KB per buffer
#define LDS_TOTAL (2 * LDS_BUF + 1024)   // 66560

__device__ __forceinline__ float tanh_fast(float x) {
  float e = __expf(2.0f * x);
  return 1.0f - 2.0f / (e + 1.0f);
}

__device__ __forceinline__ void gload_lds16(const void* g, void* l) {
  __builtin_amdgcn_global_load_lds((const __attribute__((address_space(1))) void*)g,
                                   (__attribute__((address_space(3))) void*)l, 16, 0, 0);
}

// qpb[b][a] = sum_d query[b][d]*Wq[d][a] + bq[a] + bk[a]
__global__ void k_qproj(const float* __restrict__ query, const float* __restrict__ Wq,
                        const float* __restrict__ bq, const float* __restrict__ bk,
                        float* __restrict__ qpb) {
  const int a = blockIdx.x * 256 + threadIdx.x;
  const int b = blockIdx.y;
  const float* q = query + b * SD;
  float s = 0.f;
#pragma unroll 8
  for (int d = 0; d < SD; ++d) s = fmaf(q[d], Wq[d * SD + a], s);
  qpb[b * SD + a] = s + bq[a] + bk[a];
}

// Pack Wk (f32 [K=1024][N=1024]) -> fragment-major fp16 for global_load_lds:
// per (ct 0..7, ks 0..15): 16 KB chunk = frags f=(cb*2+kk) 0..15, each
// 64 lanes x 16 B with lane = lq*16+l15: n = ct*128+cb*16+l15,
// k = ks*64 + kk*32 + lq*8 + j.
__global__ void k_packWk(const float* __restrict__ Wk, _Float16* __restrict__ WkB) {
  const int idx = blockIdx.x * 256 + threadIdx.x;   // 0..1048575
  const int k = idx >> 10, n = idx & 1023;
  const int ct = n >> 7, cb = (n >> 4) & 7, l15 = n & 15;
  const int ks = k >> 6, kk = (k >> 5) & 1, lq = (k >> 3) & 3, j = k & 7;
  WkB[(size_t)ct * 131072 + ks * 8192 + (cb * 2 + kk) * 512 + (lq * 16 + l15) * 8 + j]
      = (_Float16)Wk[idx];
}

// Main GEMM: 128x128 tile, BK=64, 4 waves (64x64 each), double-buffered LDS.
// plog[ct][m] = sum over this col-tile's 128 n of tanh(KWk + qpb)*Wa.
__global__ __launch_bounds__(256, 2) void k_main(
    const float* __restrict__ key, const _Float16* __restrict__ WkB,
    const float* __restrict__ qpb, const float* __restrict__ Wa,
    float* __restrict__ plog) {
  extern __shared__ char lds[];
  float* red = (float*)(lds + 2 * LDS_BUF);
  const int tid = threadIdx.x;
  const int wave = tid >> 6;
  const int lane = tid & 63;
  const int lane15 = lane & 15;
  const int lq = lane >> 4;
  const int wm = wave >> 1, wn = wave & 1;
  const int ct = blockIdx.x & 7;          // col-tile FAST: co-dispatched blocks share key rows
  const int rt = blockIdx.x >> 3;
  const int m0 = rt * BMm;
  const int b = m0 >> 11;

  const float4* kp = (const float4*)key + (size_t)m0 * 256;   // row stride = 256 float4

  float4 stg[8];

  // --- staging helpers ---
#define A_ISSUE(ks_) { \
  _Pragma("unroll") for (int i = 0; i < 8; ++i) { \
    const int idx = i * 256 + tid; \
    stg[i] = kp[(size_t)(idx >> 4) * 256 + (ks_) * 16 + (idx & 15)]; } }

#define A_WRITE(p_) { \
  _Pragma("unroll") for (int i = 0; i < 8; ++i) { \
    const int idx = i * 256 + tid; \
    const int row = idx >> 4, q = idx & 15; \
    f16x4 h; h[0] = (_Float16)stg[i].x; h[1] = (_Float16)stg[i].y; \
    h[2] = (_Float16)stg[i].z; h[3] = (_Float16)stg[i].w; \
    *(f16x4*)(lds + (p_) * LDS_BUF + ((row >> 4) * 2 + (q >> 3)) * 1024 \
              + (((q & 7) >> 1) * 16 + (row & 15)) * 16 + (q & 1) * 8) = h; } }

#define B_ISSUE(ks_, p_) { \
  const char* bs = (const char*)WkB + ((size_t)ct * 131072 + (size_t)(ks_) * 8192 \
                   + wave * 2048) * 2 + lane * 16; \
  char* bd = lds + (p_) * LDS_BUF + 16384 + wave * 4096; \
  _Pragma("unroll") for (int f = 0; f < 4; ++f) \
    gload_lds16(bs + f * 1024, bd + f * 1024); }

  f32x4 acc[4][4];
#pragma unroll
  for (int mt = 0; mt < 4; ++mt)
#pragma unroll
    for (int nt = 0; nt < 4; ++nt)
      acc[mt][nt] = (f32x4){0.f, 0.f, 0.f, 0.f};

  // prologue: fill buffer 0
  A_ISSUE(0); B_ISSUE(0, 0); A_WRITE(0);
  __syncthreads();

  int p = 0;
  for (int ks = 0; ks < NKS; ++ks) {
    if (ks + 1 < NKS) { A_ISSUE(ks + 1); B_ISSUE(ks + 1, p ^ 1); }
#pragma unroll
    for (int kk = 0; kk < 2; ++kk) {
      f16x8 af[4], bf[4];
#pragma unroll
      for (int mt = 0; mt < 4; ++mt)
        af[mt] = *(const f16x8*)(lds + p * LDS_BUF
                  + (((wm * 4 + mt) * 2 + kk) * 64 + lane) * 16);
#pragma unroll
      for (int nt = 0; nt < 4; ++nt)
        bf[nt] = *(const f16x8*)(lds + p * LDS_BUF + 16384
                  + (((wn * 4 + nt) * 2 + kk) * 64 + lane) * 16);
#pragma unroll
      for (int mt = 0; mt < 4; ++mt)
#pragma unroll
        for (int nt = 0; nt < 4; ++nt)
          acc[mt][nt] = __builtin_amdgcn_mfma_f32_16x16x32_f16(
              af[mt], bf[nt], acc[mt][nt], 0, 0, 0);
    }
    if (ks + 1 < NKS) A_WRITE(p ^ 1);
    __syncthreads();
    p ^= 1;
  }

  // epilogue: tanh + Wa partial dot over this wave's 64 cols
  float lp[16];
#pragma unroll
  for (int i = 0; i < 16; ++i) lp[i] = 0.f;
#pragma unroll
  for (int nt = 0; nt < 4; ++nt) {
    const int col = ct * BNn + wn * 64 + nt * 16 + lane15;
    const float qv = qpb[b * SD + col];
    const float wv = Wa[col];
#pragma unroll
    for (int mt = 0; mt < 4; ++mt)
#pragma unroll
      for (int j = 0; j < 4; ++j) {
        const float t = tanh_fast(acc[mt][nt][j] + qv);
        lp[mt * 4 + j] = fmaf(t, wv, lp[mt * 4 + j]);
      }
  }
#pragma unroll
  for (int i = 0; i < 16; ++i) {
    float v = lp[i];
    v += __shfl_xor(v, 1, 16);
    v += __shfl_xor(v, 2, 16);
    v += __shfl_xor(v, 4, 16);
    v += __shfl_xor(v, 8, 16);
    lp[i] = v;
  }
  if (lane15 == 0) {
#pragma unroll
    for (int mt = 0; mt < 4; ++mt)
#pragma unroll
      for (int j = 0; j < 4; ++j)
        red[wave * 64 + mt * 16 + lq * 4 + j] = lp[mt * 4 + j];
  }
  __syncthreads();
  if (tid < BMm) {
    const int wmr = tid >> 6, i = tid & 63;
    plog[(size_t)ct * M_TOTAL + m0 + tid]
        = red[(wmr * 2 + 0) * 64 + i] + red[(wmr * 2 + 1) * 64 + i];
  }
}

// softmax over S per batch row; input = 8 partial-logit planes, output att (fp32)
__global__ void k_softmax(const float* __restrict__ plog, float* __restrict__ att) {
  const int b = blockIdx.x, t = threadIdx.x;
  __shared__ float red[4];
  float* row = att + b * SEQ;
  float v[8];
  float mx = -3.0e38f;
#pragma unroll
  for (int i = 0; i < 8; ++i) {
    float s = 0.f;
#pragma unroll
    for (int c = 0; c < 8; ++c) s += plog[(size_t)c * M_TOTAL + b * SEQ + i * 256 + t];
    v[i] = s; mx = fmaxf(mx, s);
  }
#pragma unroll
  for (int m = 1; m < 64; m <<= 1) mx = fmaxf(mx, __shfl_xor(mx, m, 64));
  if ((t & 63) == 0) red[t >> 6] = mx;
  __syncthreads();
  mx = fmaxf(fmaxf(red[0], red[1]), fmaxf(red[2], red[3]));
  __syncthreads();
  float s = 0.f;
#pragma unroll
  for (int i = 0; i < 8; ++i) { v[i] = __expf(v[i] - mx); s += v[i]; }
#pragma unroll
  for (int m = 1; m < 64; m <<= 1) s += __shfl_xor(s, m, 64);
  if ((t & 63) == 0) red[t >> 6] = s;
  __syncthreads();
  s = red[0] + red[1] + red[2] + red[3];
  const float inv = 1.0f / s;
#pragma unroll
  for (int i = 0; i < 8; ++i) row[i * 256 + t] = v[i] * inv;
}

// context partials: 16 s-slices per batch
__global__ void k_ctx(const float* __restrict__ value, const float* __restrict__ att,
                      float4* __restrict__ partials) {
  const int bx = blockIdx.x;
  const int b = bx >> 4, sl = bx & 15;
  const int t = threadIdx.x;
  const float4* vp = (const float4*)(value + (size_t)(b * SEQ + sl * 128) * SD);
  const float* ap = att + b * SEQ + sl * 128;
  float4 acc = make_float4(0.f, 0.f, 0.f, 0.f);
#pragma unroll 4
  for (int s = 0; s < 128; ++s) {
    const float w = ap[s];
    const float4 v = vp[s * 256 + t];
    acc.x = fmaf(w, v.x, acc.x); acc.y = fmaf(w, v.y, acc.y);
    acc.z = fmaf(w, v.z, acc.z); acc.w = fmaf(w, v.w, acc.w);
  }
  partials[(b * 16 + sl) * 256 + t] = acc;
}

__global__ void k_fin(const float* __restrict__ partials, float* __restrict__ ctx) {
  const int i = blockIdx.x * 256 + threadIdx.x;  // 0..32767
  const int b = i >> 10, d = i & 1023;
  float s = 0.f;
#pragma unroll
  for (int sl = 0; sl < 16; ++sl) s += partials[(b * 16 + sl) * SD + d];
  ctx[i] = s;
}

extern "C" void kernel_launch(void* const* d_in, const int* in_sizes, int n_in,
                              void* d_out, int out_size, void* d_ws, size_t ws_size,
                              hipStream_t stream) {
  const float* query = (const float*)d_in[0];
  const float* key   = (const float*)d_in[1];
  const float* value = (const float*)d_in[2];
  const float* Wq    = (const float*)d_in[3];
  const float* bq    = (const float*)d_in[4];
  const float* Wk    = (const float*)d_in[5];
  const float* bk    = (const float*)d_in[6];
  const float* Wa    = (const float*)d_in[7];
  // ba (d_in[8]) is softmax-invariant -> dropped.

  float* out = (float*)d_out;
  float* ctx_out = out;               // [32][1024]
  float* att_out = out + NB * SD;     // [32][2048]

  char* ws = (char*)d_ws;
  float* qpb = (float*)ws;                           // 128 KB @ 0
  _Float16* WkB = (_Float16*)(ws + 131072);          // 2 MB   @ 128 KB
  float* plog = (float*)(ws + 131072 + 2097152);     // 2 MB   @ 2.125 MB
  float* partials = (float*)(ws + 131072);           // aliases WkB (k_ctx runs after k_main)

  hipFuncSetAttribute(reinterpret_cast<const void*>(k_main),
                      hipFuncAttributeMaxDynamicSharedMemorySize, LDS_TOTAL);

  k_qproj<<<dim3(4, NB), 256, 0, stream>>>(query, Wq, bq, bk, qpb);
  k_packWk<<<4096, 256, 0, stream>>>(Wk, WkB);
  k_main<<<NRT * NCT, 256, LDS_TOTAL, stream>>>(key, WkB, qpb, Wa, plog);
  k_softmax<<<NB, 256, 0, stream>>>(plog, att_out);
  k_ctx<<<NB * 16, 256, 0, stream>>>(value, att_out, (float4*)partials);
  k_fin<<<NB * SD / 256, 256, 0, stream>>>(partials, ctx_out);
}